// Round 3
// baseline (3640.970 us; speedup 1.0000x reference)
//
#include <hip/hip_runtime.h>
#include <cmath>

#define D 64

__device__ __forceinline__ float wave_reduce_sum(float v) {
  #pragma unroll
  for (int off = 32; off > 0; off >>= 1) v += __shfl_xor(v, off, 64);
  return v;
}
__device__ __forceinline__ float wave_reduce_max(float v) {
  #pragma unroll
  for (int off = 32; off > 0; off >>= 1) v = fmaxf(v, __shfl_xor(v, off, 64));
  return v;
}

// ---------------- CSR build ----------------

__global__ void mark_usel(const int* __restrict__ uid, int* __restrict__ usel, int B) {
  int b = blockIdx.x * blockDim.x + threadIdx.x;
  if (b < B) usel[uid[b]] = 1;
}

// histogram of src; optionally drop user-side rows not in usel (uk graph)
__global__ void hist_src(const int* __restrict__ src, int* __restrict__ deg, int n,
                         const int* __restrict__ usel, int filt, int NU) {
  int e = blockIdx.x * blockDim.x + threadIdx.x;
  if (e >= n) return;
  int s = src[e];
  if (filt && s < NU && usel[s] == 0) return;
  atomicAdd(&deg[s], 1);
}

// single-block hierarchical exclusive scan: rowptr[N+1], cursor copy
__global__ __launch_bounds__(1024) void scan_rowptr(const int* __restrict__ deg,
                                                    int* __restrict__ rowptr,
                                                    int* __restrict__ cursor, int N) {
  __shared__ int partial[1024];
  int tid = threadIdx.x;
  int chunk = (N + 1023) / 1024;
  int lo = tid * chunk, hi = min(lo + chunk, N);
  int s = 0;
  for (int i = lo; i < hi; ++i) s += deg[i];
  partial[tid] = s;
  __syncthreads();
  for (int off = 1; off < 1024; off <<= 1) {
    int v = (tid >= off) ? partial[tid - off] : 0;
    __syncthreads();
    partial[tid] += v;
    __syncthreads();
  }
  int run = (tid > 0) ? partial[tid - 1] : 0;
  for (int i = lo; i < hi; ++i) {
    rowptr[i] = run; cursor[i] = run;
    run += deg[i];
  }
  if (tid == 1023) rowptr[N] = run;
}

// scatter (dst,val) records into CSR order
__global__ void scatter_edges(const int* __restrict__ src, const int* __restrict__ dst,
                              const float* __restrict__ vals, int* __restrict__ cursor,
                              int2* __restrict__ edata, int n,
                              const int* __restrict__ usel, int filt, int NU) {
  int e = blockIdx.x * blockDim.x + threadIdx.x;
  if (e >= n) return;
  int s = src[e];
  if (filt && s < NU && usel[s] == 0) return;
  int pos = atomicAdd(&cursor[s], 1);
  edata[pos] = make_int2(dst[e], __float_as_int(vals[e]));
}

// ---------------- SpMM (wave per row, no atomics) ----------------

// layer 1 over rows [row0, row0+nrows): l1[r] = sum_j val_j * feat0(dst_j)
__global__ void spmm_l1(const int* __restrict__ rowptr, const int2* __restrict__ edata,
                        const float* __restrict__ userF, const float* __restrict__ itemF,
                        float* __restrict__ l1, int row0, int nrows, int NU) {
  int r = row0 + blockIdx.x * 4 + (threadIdx.x >> 6);
  if (r >= row0 + nrows) return;
  int d = threadIdx.x & 63;
  int lo = rowptr[r], hi = rowptr[r + 1];
  float acc = 0.f;
  for (int j = lo; j < hi; ++j) {
    int2 ed = edata[j];
    int t = ed.x; float v = __int_as_float(ed.y);
    const float* f = (t < NU) ? (userF + (size_t)t * D) : (itemF + (size_t)(t - NU) * D);
    acc = fmaf(v, f[d], acc);
  }
  l1[(size_t)r * D + d] = acc;
}

// layer 1 only at the batch user rows (uk graph): l1[uid[b]] = row sum
__global__ void spmm_l1_uid(const int* __restrict__ rowptr, const int2* __restrict__ edata,
                            const float* __restrict__ userF, const float* __restrict__ itemF,
                            float* __restrict__ l1, const int* __restrict__ uid, int B, int NU) {
  int b = blockIdx.x * 4 + (threadIdx.x >> 6);
  if (b >= B) return;
  int d = threadIdx.x & 63;
  int r = uid[b];
  int lo = rowptr[r], hi = rowptr[r + 1];
  float acc = 0.f;
  for (int j = lo; j < hi; ++j) {
    int2 ed = edata[j];
    int t = ed.x; float v = __int_as_float(ed.y);
    const float* f = (t < NU) ? (userF + (size_t)t * D) : (itemF + (size_t)(t - NU) * D);
    acc = fmaf(v, f[d], acc);
  }
  l1[(size_t)r * D + d] = acc;  // duplicate uids write identical values: benign
}

// fused layer-2 + average for item rows: out[i] = (itemF + l1[NU+i] + sum val*l1[dst]) / 3
__global__ void final_item(const int* __restrict__ rowptr, const int2* __restrict__ edata,
                           const float* __restrict__ l1, const float* __restrict__ itemF,
                           float* __restrict__ out, int NU, int NI) {
  int i = blockIdx.x * 4 + (threadIdx.x >> 6);
  if (i >= NI) return;
  int d = threadIdx.x & 63;
  int r = NU + i;
  int lo = rowptr[r], hi = rowptr[r + 1];
  float acc = 0.f;
  for (int j = lo; j < hi; ++j) {
    int2 ed = edata[j];
    acc = fmaf(__int_as_float(ed.y), l1[(size_t)ed.x * D + d], acc);
  }
  out[(size_t)i * D + d] = (itemF[(size_t)i * D + d] + l1[(size_t)r * D + d] + acc) * (1.f / 3.f);
}

// fused layer-2 + average for the B batch users: ug[b] (+)= (userF + l1[u] + sum val*l1[dst]) / 3
__global__ void final_uid(const int* __restrict__ rowptr, const int2* __restrict__ edata,
                          const float* __restrict__ l1, const float* __restrict__ userF,
                          const int* __restrict__ uid, float* __restrict__ ug, int add, int B) {
  int b = blockIdx.x * 4 + (threadIdx.x >> 6);
  if (b >= B) return;
  int d = threadIdx.x & 63;
  int u = uid[b];
  int lo = rowptr[u], hi = rowptr[u + 1];
  float acc = 0.f;
  for (int j = lo; j < hi; ++j) {
    int2 ed = edata[j];
    acc = fmaf(__int_as_float(ed.y), l1[(size_t)ed.x * D + d], acc);
  }
  float res = (userF[(size_t)u * D + d] + l1[(size_t)u * D + d] + acc) * (1.f / 3.f);
  if (add) ug[(size_t)b * D + d] += res; else ug[(size_t)b * D + d] = res;
}

// ---------------- fused attention + MLP + output ----------------

__global__ __launch_bounds__(64) void attn_final(
    const float* __restrict__ e1, const float* __restrict__ pe,
    const int* __restrict__ seq, const int* __restrict__ mask,
    const float* __restrict__ wq_w, const float* __restrict__ wq_b,
    const float* __restrict__ wk_w, const float* __restrict__ wk_b,
    const float* __restrict__ wv_w, const float* __restrict__ wv_b,
    const float* __restrict__ mlp_w, const float* __restrict__ mlp_b,
    const float* __restrict__ ug, const float* __restrict__ c1,
    const int* __restrict__ cid, float* __restrict__ out, int T) {
  __shared__ float xs[64][D];
  __shared__ float wks[D * D];
  __shared__ float wvs[D * D];
  __shared__ float ps[D];
  __shared__ float ys[D];
  __shared__ float atts[D];
  int b = blockIdx.x, d = threadIdx.x;

  for (int i = d; i < D * D; i += 64) { wks[i] = wk_w[i]; wvs[i] = wv_w[i]; }
  for (int t = 0; t < T; ++t) {
    int sidx = seq[b * T + t];
    xs[t][d] = e1[(size_t)sidx * D + d] + pe[t * D + d];
  }
  __syncthreads();

  float qd = wq_b[d];
  #pragma unroll 4
  for (int j = 0; j < D; ++j) qd = fmaf(xs[T - 1][j], wq_w[j * D + d], qd);
  if (mask[b * T + (T - 1)] == 0) qd = -100000.0f;

  float my_score = -INFINITY;
  for (int t = 0; t < T; ++t) {
    float kd = wk_b[d];
    #pragma unroll 8
    for (int j = 0; j < D; ++j) kd = fmaf(xs[t][j], wks[j * D + d], kd);
    if (mask[b * T + t] == 0) kd = -100000.0f;
    float s = wave_reduce_sum(qd * kd) * 0.125f;
    if (d == t) my_score = s;
  }
  float m = wave_reduce_max(my_score);
  float p = (d < T) ? expf(my_score - m) : 0.f;
  float sum = wave_reduce_sum(p);
  ps[d] = p / sum;
  __syncthreads();

  float yj = 0.f;
  for (int t = 0; t < T; ++t) yj = fmaf(ps[t], xs[t][d], yj);
  ys[d] = yj;
  __syncthreads();
  float ad = wv_b[d];
  #pragma unroll 8
  for (int j = 0; j < D; ++j) ad = fmaf(ys[j], wvs[j * D + d], ad);
  atts[d] = ad;
  __syncthreads();

  float h = mlp_b[d];
  #pragma unroll 4
  for (int j = 0; j < D; ++j) h = fmaf(ug[(size_t)b * D + j], mlp_w[j * D + d], h);
  #pragma unroll 4
  for (int j = 0; j < D; ++j) h = fmaf(atts[j], mlp_w[(D + j) * D + d], h);
  h = fmaxf(h, 0.f);

  #pragma unroll
  for (int c = 0; c < 2; ++c) {
    int cc = cid[b * 2 + c];
    float s = wave_reduce_sum(h * c1[(size_t)cc * D + d]);
    if (d == 0) out[b * 2 + c] = s;
  }
}

// ---------------- host ----------------

extern "C" void kernel_launch(void* const* d_in, const int* in_sizes, int n_in,
                              void* d_out, int out_size, void* d_ws, size_t ws_size,
                              hipStream_t stream) {
  const float* usersF   = (const float*)d_in[0];
  const float* coursesF = (const float*)d_in[1];
  const float* exF      = (const float*)d_in[2];
  const float* knF      = (const float*)d_in[3];
  const float* wq_w = (const float*)d_in[4];
  const float* wq_b = (const float*)d_in[5];
  const float* wk_w = (const float*)d_in[6];
  const float* wk_b = (const float*)d_in[7];
  const float* wv_w = (const float*)d_in[8];
  const float* wv_b = (const float*)d_in[9];
  const float* mlp_w = (const float*)d_in[10];
  const float* mlp_b = (const float*)d_in[11];
  const float* pe = (const float*)d_in[12];
  const float* uc_vals = (const float*)d_in[13];
  const float* ue_vals = (const float*)d_in[14];
  const float* uk_vals = (const float*)d_in[15];
  const int* uc_src = (const int*)d_in[16];
  const int* uc_dst = (const int*)d_in[17];
  const int* ue_src = (const int*)d_in[18];
  const int* ue_dst = (const int*)d_in[19];
  const int* uk_src = (const int*)d_in[20];
  const int* uk_dst = (const int*)d_in[21];
  const int* mask = (const int*)d_in[22];
  const int* seq  = (const int*)d_in[23];
  const int* uid  = (const int*)d_in[24];
  const int* cid  = (const int*)d_in[25];

  int NU = in_sizes[0] / D;
  int NC = in_sizes[1] / D;
  int NE = in_sizes[2] / D;
  int NK = in_sizes[3] / D;
  int B  = in_sizes[24];
  int T  = in_sizes[22] / B;
  int n2_uc = in_sizes[13], n2_ue = in_sizes[14], n2_uk = in_sizes[15];

  int NImax = NC > NE ? NC : NE; NImax = NImax > NK ? NImax : NK;
  int Nmax = NU + NImax;
  int n2max = n2_uc > n2_ue ? n2_uc : n2_ue; n2max = n2max > n2_uk ? n2max : n2_uk;

  char* w = (char*)d_ws;
  auto alloc = [&](size_t bytes) { void* p = (void*)w; w += (bytes + 255) & ~(size_t)255; return p; };
  int2*  edata  = (int2*)alloc((size_t)n2max * 8);
  float* l1     = (float*)alloc((size_t)Nmax * D * 4);
  float* e1     = (float*)alloc((size_t)NE * D * 4);
  float* c1     = (float*)alloc((size_t)NC * D * 4);
  float* ug     = (float*)alloc((size_t)B * D * 4);
  int*   rowptr = (int*)alloc((size_t)(Nmax + 1) * 4);
  int*   deg    = (int*)alloc((size_t)Nmax * 4);
  int*   cursor = (int*)alloc((size_t)Nmax * 4);
  int*   usel   = (int*)alloc((size_t)NU * 4);

  hipMemsetAsync(usel, 0, (size_t)NU * 4, stream);
  mark_usel<<<(B + 255) / 256, 256, 0, stream>>>(uid, usel, B);

  auto run_graph = [&](const int* src, const int* dst, const float* vals, int n2,
                       int NI, const float* itemF, int filt, float* itemOut, int add) {
    int N = NU + NI;
    unsigned eg = (unsigned)((n2 + 255) / 256);
    hipMemsetAsync(deg, 0, (size_t)N * 4, stream);
    hist_src<<<eg, 256, 0, stream>>>(src, deg, n2, usel, filt, NU);
    scan_rowptr<<<1, 1024, 0, stream>>>(deg, rowptr, cursor, N);
    scatter_edges<<<eg, 256, 0, stream>>>(src, dst, vals, cursor, edata, n2, usel, filt, NU);
    if (!filt) {
      spmm_l1<<<(unsigned)((N + 3) / 4), 256, 0, stream>>>(rowptr, edata, usersF, itemF, l1, 0, N, NU);
    } else {
      spmm_l1<<<(unsigned)((NI + 3) / 4), 256, 0, stream>>>(rowptr, edata, usersF, itemF, l1, NU, NI, NU);
      spmm_l1_uid<<<(unsigned)((B + 3) / 4), 256, 0, stream>>>(rowptr, edata, usersF, itemF, l1, uid, B, NU);
    }
    if (itemOut)
      final_item<<<(unsigned)((NI + 3) / 4), 256, 0, stream>>>(rowptr, edata, l1, itemF, itemOut, NU, NI);
    final_uid<<<(unsigned)((B + 3) / 4), 256, 0, stream>>>(rowptr, edata, l1, usersF, uid, ug, add, B);
  };

  run_graph(uc_src, uc_dst, uc_vals, n2_uc, NC, coursesF, 0, c1, 0);
  run_graph(ue_src, ue_dst, ue_vals, n2_ue, NE, exF,      0, e1, 1);
  run_graph(uk_src, uk_dst, uk_vals, n2_uk, NK, knF,      1, nullptr, 1);

  attn_final<<<B, 64, 0, stream>>>(e1, pe, seq, mask, wq_w, wq_b, wk_w, wk_b,
                                   wv_w, wv_b, mlp_w, mlp_b, ug, c1, cid, (float*)d_out, T);
}

// Round 4
// 1918.659 us; speedup vs baseline: 1.8977x; 1.8977x over previous
//
#include <hip/hip_runtime.h>
#include <cmath>

#define D 64

__device__ __forceinline__ float wave_reduce_sum(float v) {
  #pragma unroll
  for (int off = 32; off > 0; off >>= 1) v += __shfl_xor(v, off, 64);
  return v;
}
__device__ __forceinline__ float wave_reduce_max(float v) {
  #pragma unroll
  for (int off = 32; off > 0; off >>= 1) v = fmaxf(v, __shfl_xor(v, off, 64));
  return v;
}
__device__ __forceinline__ int wave_reduce_sum_i(int v) {
  #pragma unroll
  for (int off = 32; off > 0; off >>= 1) v += __shfl_xor(v, off, 64);
  return v;
}

// Core: accumulate one CSR row with 4 edge-groups x 16 columns, 8 edges/iter.
// After call: caller must cross-group reduce. Lane layout: g = lane>>4, c = lane&15.
// acc[k] holds partial for column c + 16*k from this lane's group.
__device__ __forceinline__ void row_accum(const int2* __restrict__ edata, int lo, int hi,
                                          const float* __restrict__ ftab,
                                          int g, int c,
                                          float& a0, float& a1, float& a2, float& a3) {
  for (int base = lo; base < hi; base += 8) {
    int j0 = base + g, j1 = base + 4 + g;
    int2 e0 = (j0 < hi) ? edata[j0] : make_int2(0, 0);
    int2 e1 = (j1 < hi) ? edata[j1] : make_int2(0, 0);
    const float* f0 = ftab + (size_t)e0.x * D + c;
    const float* f1 = ftab + (size_t)e1.x * D + c;
    float v0 = __int_as_float(e0.y), v1 = __int_as_float(e1.y);
    a0 = fmaf(v0, f0[0],  a0); a1 = fmaf(v0, f0[16], a1);
    a2 = fmaf(v0, f0[32], a2); a3 = fmaf(v0, f0[48], a3);
    a0 = fmaf(v1, f1[0],  a0); a1 = fmaf(v1, f1[16], a1);
    a2 = fmaf(v1, f1[32], a2); a3 = fmaf(v1, f1[48], a3);
  }
}

__device__ __forceinline__ float cross_group_reduce(float a0, float a1, float a2, float a3, int g) {
  a0 += __shfl_xor(a0, 16, 64); a0 += __shfl_xor(a0, 32, 64);
  a1 += __shfl_xor(a1, 16, 64); a1 += __shfl_xor(a1, 32, 64);
  a2 += __shfl_xor(a2, 16, 64); a2 += __shfl_xor(a2, 32, 64);
  a3 += __shfl_xor(a3, 16, 64); a3 += __shfl_xor(a3, 32, 64);
  float r = (g == 0) ? a0 : (g == 1) ? a1 : (g == 2) ? a2 : a3;
  return r;  // lane L now holds full sum for column L
}

// ---------------- CSR build ----------------

__global__ void mark_usel(const int* __restrict__ uid, int* __restrict__ usel, int B) {
  int b = blockIdx.x * blockDim.x + threadIdx.x;
  if (b < B) usel[uid[b]] = 1;
}

__global__ void hist_src(const int* __restrict__ src, int* __restrict__ deg, int n, int h,
                         const int* __restrict__ usel, int filt) {
  int e = blockIdx.x * blockDim.x + threadIdx.x;
  if (e >= n) return;
  int s = src[e];
  if (filt && e < h && usel[s] == 0) return;
  atomicAdd(&deg[s], 1);
}

// ---- coalesced 3-pass scan (exclusive) over deg[N] -> rowptr[N+1], cursor[N] ----
#define SCHUNK 2048

__global__ void scan_p1(const int* __restrict__ deg, int* __restrict__ bsum, int N) {
  int b = blockIdx.x, t = threadIdx.x;
  int lo = b * SCHUNK;
  int s = 0;
  #pragma unroll
  for (int k = 0; k < 8; ++k) { int i = lo + k * 256 + t; if (i < N) s += deg[i]; }
  s = wave_reduce_sum_i(s);
  __shared__ int ws[4];
  if ((t & 63) == 0) ws[t >> 6] = s;
  __syncthreads();
  if (t == 0) bsum[b] = ws[0] + ws[1] + ws[2] + ws[3];
}

__global__ __launch_bounds__(1024) void scan_p2(int* __restrict__ bsum, int nb,
                                                int* __restrict__ rowptr, int N) {
  __shared__ int arr[1024];
  int t = threadIdx.x;
  int v = (t < nb) ? bsum[t] : 0;
  arr[t] = v; __syncthreads();
  for (int off = 1; off < 1024; off <<= 1) {
    int x = (t >= off) ? arr[t - off] : 0;
    __syncthreads();
    arr[t] += x;
    __syncthreads();
  }
  if (t < nb) bsum[t] = t ? arr[t - 1] : 0;   // exclusive block offsets
  if (t == 0) rowptr[N] = arr[nb - 1];        // total
}

__global__ void scan_p3(const int* __restrict__ deg, const int* __restrict__ bsum,
                        int* __restrict__ rowptr, int* __restrict__ cursor, int N) {
  int b = blockIdx.x, t = threadIdx.x;
  int lane = t & 63, wid = t >> 6;
  int base = b * SCHUNK + t * 8;
  int x[8], excl[8], s = 0;
  #pragma unroll
  for (int k = 0; k < 8; ++k) x[k] = (base + k < N) ? deg[base + k] : 0;
  #pragma unroll
  for (int k = 0; k < 8; ++k) { excl[k] = s; s += x[k]; }
  int incl = s;
  #pragma unroll
  for (int off = 1; off < 64; off <<= 1) {
    int y = __shfl_up(incl, off, 64);
    if (lane >= off) incl += y;
  }
  int wave_excl = incl - s;
  __shared__ int wsumS[4];
  if (lane == 63) wsumS[wid] = incl;
  __syncthreads();
  int wo = 0;
  for (int w = 0; w < wid; ++w) wo += wsumS[w];
  int off0 = bsum[b] + wo + wave_excl;
  #pragma unroll
  for (int k = 0; k < 8; ++k) {
    int i = base + k;
    if (i < N) { rowptr[i] = off0 + excl[k]; cursor[i] = off0 + excl[k]; }
  }
}

// scatter (local_dst, val) records into CSR order
__global__ void scatter_edges(const int* __restrict__ src, const int* __restrict__ dst,
                              const float* __restrict__ vals, int* __restrict__ cursor,
                              int2* __restrict__ edata, int n, int h, int NU,
                              const int* __restrict__ usel, int filt) {
  int e = blockIdx.x * blockDim.x + threadIdx.x;
  if (e >= n) return;
  int s = src[e];
  if (filt && e < h && usel[s] == 0) return;
  int t = dst[e];
  if (e < h) t -= NU;  // first half: dst is item-global -> make local. second half: already user-local
  int pos = atomicAdd(&cursor[s], 1);
  edata[pos] = make_int2(t, __float_as_int(vals[e]));
}

// ---------------- SpMM layer kernels (wave/row, 4x16 edge groups) ----------------

// layer1 rows [row0, row0+nrows): user rows gather itemF -> ul1 ; item rows gather userF -> il1
__global__ void spmm_l1(const int* __restrict__ rowptr, const int2* __restrict__ edata,
                        const float* __restrict__ userF, const float* __restrict__ itemF,
                        float* __restrict__ ul1, float* __restrict__ il1,
                        int row0, int nrows, int NU) {
  int r = row0 + blockIdx.x * 4 + (threadIdx.x >> 6);
  if (r >= row0 + nrows) return;
  int lane = threadIdx.x & 63, g = lane >> 4, c = lane & 15;
  const float* ftab = (r < NU) ? itemF : userF;
  float a0 = 0.f, a1 = 0.f, a2 = 0.f, a3 = 0.f;
  row_accum(edata, rowptr[r], rowptr[r + 1], ftab, g, c, a0, a1, a2, a3);
  float v = cross_group_reduce(a0, a1, a2, a3, g);
  float* out = (r < NU) ? (ul1 + (size_t)r * D) : (il1 + (size_t)(r - NU) * D);
  out[lane] = v;
}

// layer1 only at batch user rows (uk): ul1[uid[b]] = row sum (gathers itemF)
__global__ void spmm_l1_uid(const int* __restrict__ rowptr, const int2* __restrict__ edata,
                            const float* __restrict__ itemF, float* __restrict__ ul1,
                            const int* __restrict__ uid, int B) {
  int b = blockIdx.x * 4 + (threadIdx.x >> 6);
  if (b >= B) return;
  int lane = threadIdx.x & 63, g = lane >> 4, c = lane & 15;
  int r = uid[b];
  float a0 = 0.f, a1 = 0.f, a2 = 0.f, a3 = 0.f;
  row_accum(edata, rowptr[r], rowptr[r + 1], itemF, g, c, a0, a1, a2, a3);
  float v = cross_group_reduce(a0, a1, a2, a3, g);
  ul1[(size_t)r * D + lane] = v;  // duplicate uids write identical values: benign
}

// layer2+avg for item rows: out[i] = (itemF + il1[i] + sum val*ul1[dst]) / 3
__global__ void final_item(const int* __restrict__ rowptr, const int2* __restrict__ edata,
                           const float* __restrict__ ul1, const float* __restrict__ il1,
                           const float* __restrict__ itemF, float* __restrict__ out,
                           int NU, int NI) {
  int i = blockIdx.x * 4 + (threadIdx.x >> 6);
  if (i >= NI) return;
  int lane = threadIdx.x & 63, g = lane >> 4, c = lane & 15;
  int r = NU + i;
  float a0 = 0.f, a1 = 0.f, a2 = 0.f, a3 = 0.f;
  row_accum(edata, rowptr[r], rowptr[r + 1], ul1, g, c, a0, a1, a2, a3);
  float v = cross_group_reduce(a0, a1, a2, a3, g);
  size_t o = (size_t)i * D + lane;
  out[o] = (itemF[o] + il1[o] + v) * (1.f / 3.f);
}

// layer2+avg at batch users: ug[b] (+)= (userF[u] + ul1[u] + sum val*il1[dst]) / 3
__global__ void final_uid(const int* __restrict__ rowptr, const int2* __restrict__ edata,
                          const float* __restrict__ il1, const float* __restrict__ ul1,
                          const float* __restrict__ userF, const int* __restrict__ uid,
                          float* __restrict__ ug, int add, int B) {
  int b = blockIdx.x * 4 + (threadIdx.x >> 6);
  if (b >= B) return;
  int lane = threadIdx.x & 63, g = lane >> 4, c = lane & 15;
  int u = uid[b];
  float a0 = 0.f, a1 = 0.f, a2 = 0.f, a3 = 0.f;
  row_accum(edata, rowptr[u], rowptr[u + 1], il1, g, c, a0, a1, a2, a3);
  float v = cross_group_reduce(a0, a1, a2, a3, g);
  size_t uo = (size_t)u * D + lane;
  float res = (userF[uo] + ul1[uo] + v) * (1.f / 3.f);
  if (add) ug[(size_t)b * D + lane] += res; else ug[(size_t)b * D + lane] = res;
}

// ---------------- fused attention + MLP + output ----------------

__global__ __launch_bounds__(64) void attn_final(
    const float* __restrict__ e1, const float* __restrict__ pe,
    const int* __restrict__ seq, const int* __restrict__ mask,
    const float* __restrict__ wq_w, const float* __restrict__ wq_b,
    const float* __restrict__ wk_w, const float* __restrict__ wk_b,
    const float* __restrict__ wv_w, const float* __restrict__ wv_b,
    const float* __restrict__ mlp_w, const float* __restrict__ mlp_b,
    const float* __restrict__ ug, const float* __restrict__ c1,
    const int* __restrict__ cid, float* __restrict__ out, int T) {
  __shared__ float xs[64][D];
  __shared__ float wks[D * D];
  __shared__ float wvs[D * D];
  __shared__ float ps[D];
  __shared__ float ys[D];
  __shared__ float atts[D];
  int b = blockIdx.x, d = threadIdx.x;

  for (int i = d; i < D * D; i += 64) { wks[i] = wk_w[i]; wvs[i] = wv_w[i]; }
  for (int t = 0; t < T; ++t) {
    int sidx = seq[b * T + t];
    xs[t][d] = e1[(size_t)sidx * D + d] + pe[t * D + d];
  }
  __syncthreads();

  float qd = wq_b[d];
  #pragma unroll 4
  for (int j = 0; j < D; ++j) qd = fmaf(xs[T - 1][j], wq_w[j * D + d], qd);
  if (mask[b * T + (T - 1)] == 0) qd = -100000.0f;

  float my_score = -INFINITY;
  for (int t = 0; t < T; ++t) {
    float kd = wk_b[d];
    #pragma unroll 8
    for (int j = 0; j < D; ++j) kd = fmaf(xs[t][j], wks[j * D + d], kd);
    if (mask[b * T + t] == 0) kd = -100000.0f;
    float s = wave_reduce_sum(qd * kd) * 0.125f;
    if (d == t) my_score = s;
  }
  float m = wave_reduce_max(my_score);
  float p = (d < T) ? expf(my_score - m) : 0.f;
  float sum = wave_reduce_sum(p);
  ps[d] = p / sum;
  __syncthreads();

  float yj = 0.f;
  for (int t = 0; t < T; ++t) yj = fmaf(ps[t], xs[t][d], yj);
  ys[d] = yj;
  __syncthreads();
  float ad = wv_b[d];
  #pragma unroll 8
  for (int j = 0; j < D; ++j) ad = fmaf(ys[j], wvs[j * D + d], ad);
  atts[d] = ad;
  __syncthreads();

  float h = mlp_b[d];
  #pragma unroll 4
  for (int j = 0; j < D; ++j) h = fmaf(ug[(size_t)b * D + j], mlp_w[j * D + d], h);
  #pragma unroll 4
  for (int j = 0; j < D; ++j) h = fmaf(atts[j], mlp_w[(D + j) * D + d], h);
  h = fmaxf(h, 0.f);

  #pragma unroll
  for (int c = 0; c < 2; ++c) {
    int cc = cid[b * 2 + c];
    float s = wave_reduce_sum(h * c1[(size_t)cc * D + d]);
    if (d == 0) out[b * 2 + c] = s;
  }
}

// ---------------- host ----------------

extern "C" void kernel_launch(void* const* d_in, const int* in_sizes, int n_in,
                              void* d_out, int out_size, void* d_ws, size_t ws_size,
                              hipStream_t stream) {
  const float* usersF   = (const float*)d_in[0];
  const float* coursesF = (const float*)d_in[1];
  const float* exF      = (const float*)d_in[2];
  const float* knF      = (const float*)d_in[3];
  const float* wq_w = (const float*)d_in[4];
  const float* wq_b = (const float*)d_in[5];
  const float* wk_w = (const float*)d_in[6];
  const float* wk_b = (const float*)d_in[7];
  const float* wv_w = (const float*)d_in[8];
  const float* wv_b = (const float*)d_in[9];
  const float* mlp_w = (const float*)d_in[10];
  const float* mlp_b = (const float*)d_in[11];
  const float* pe = (const float*)d_in[12];
  const float* uc_vals = (const float*)d_in[13];
  const float* ue_vals = (const float*)d_in[14];
  const float* uk_vals = (const float*)d_in[15];
  const int* uc_src = (const int*)d_in[16];
  const int* uc_dst = (const int*)d_in[17];
  const int* ue_src = (const int*)d_in[18];
  const int* ue_dst = (const int*)d_in[19];
  const int* uk_src = (const int*)d_in[20];
  const int* uk_dst = (const int*)d_in[21];
  const int* mask = (const int*)d_in[22];
  const int* seq  = (const int*)d_in[23];
  const int* uid  = (const int*)d_in[24];
  const int* cid  = (const int*)d_in[25];

  int NU = in_sizes[0] / D;
  int NC = in_sizes[1] / D;
  int NE = in_sizes[2] / D;
  int NK = in_sizes[3] / D;
  int B  = in_sizes[24];
  int T  = in_sizes[22] / B;
  int n2_uc = in_sizes[13], n2_ue = in_sizes[14], n2_uk = in_sizes[15];

  int NImax = NC > NE ? NC : NE; NImax = NImax > NK ? NImax : NK;
  int Nmax = NU + NImax;
  int n2max = n2_uc > n2_ue ? n2_uc : n2_ue; n2max = n2max > n2_uk ? n2max : n2_uk;

  char* w = (char*)d_ws;
  auto alloc = [&](size_t bytes) { void* p = (void*)w; w += (bytes + 255) & ~(size_t)255; return p; };
  int2*  edata  = (int2*)alloc((size_t)n2max * 8);
  float* ul1    = (float*)alloc((size_t)NU * D * 4);
  float* il1    = (float*)alloc((size_t)NImax * D * 4);
  float* e1     = (float*)alloc((size_t)NE * D * 4);
  float* c1     = (float*)alloc((size_t)NC * D * 4);
  float* ug     = (float*)alloc((size_t)B * D * 4);
  int*   rowptr = (int*)alloc((size_t)(Nmax + 1) * 4);
  int*   deg    = (int*)alloc((size_t)Nmax * 4);
  int*   cursor = (int*)alloc((size_t)Nmax * 4);
  int*   usel   = (int*)alloc((size_t)NU * 4);
  int*   bsum   = (int*)alloc((size_t)1024 * 4);

  hipMemsetAsync(usel, 0, (size_t)NU * 4, stream);
  mark_usel<<<(B + 255) / 256, 256, 0, stream>>>(uid, usel, B);

  auto run_graph = [&](const int* src, const int* dst, const float* vals, int n2,
                       int NI, const float* itemF, int filt, float* itemOut, int add) {
    int N = NU + NI;
    int h = n2 / 2;
    unsigned eg = (unsigned)((n2 + 255) / 256);
    int nb = (N + SCHUNK - 1) / SCHUNK;
    hipMemsetAsync(deg, 0, (size_t)N * 4, stream);
    hist_src<<<eg, 256, 0, stream>>>(src, deg, n2, h, usel, filt);
    scan_p1<<<(unsigned)nb, 256, 0, stream>>>(deg, bsum, N);
    scan_p2<<<1, 1024, 0, stream>>>(bsum, nb, rowptr, N);
    scan_p3<<<(unsigned)nb, 256, 0, stream>>>(deg, bsum, rowptr, cursor, N);
    scatter_edges<<<eg, 256, 0, stream>>>(src, dst, vals, cursor, edata, n2, h, NU, usel, filt);
    if (!filt) {
      spmm_l1<<<(unsigned)((N + 3) / 4), 256, 0, stream>>>(rowptr, edata, usersF, itemF, ul1, il1, 0, N, NU);
    } else {
      spmm_l1<<<(unsigned)((NI + 3) / 4), 256, 0, stream>>>(rowptr, edata, usersF, itemF, ul1, il1, NU, NI, NU);
      spmm_l1_uid<<<(unsigned)((B + 3) / 4), 256, 0, stream>>>(rowptr, edata, itemF, ul1, uid, B);
    }
    if (itemOut)
      final_item<<<(unsigned)((NI + 3) / 4), 256, 0, stream>>>(rowptr, edata, ul1, il1, itemF, itemOut, NU, NI);
    final_uid<<<(unsigned)((B + 3) / 4), 256, 0, stream>>>(rowptr, edata, il1, ul1, usersF, uid, ug, add, B);
  };

  run_graph(uc_src, uc_dst, uc_vals, n2_uc, NC, coursesF, 0, c1, 0);
  run_graph(ue_src, ue_dst, ue_vals, n2_ue, NE, exF,      0, e1, 1);
  run_graph(uk_src, uk_dst, uk_vals, n2_uk, NK, knF,      1, nullptr, 1);

  attn_final<<<B, 64, 0, stream>>>(e1, pe, seq, mask, wq_w, wq_b, wk_w, wk_b,
                                   wv_w, wv_b, mlp_w, mlp_b, ug, c1, cid, (float*)d_out, T);
}